// Round 2
// baseline (7729.224 us; speedup 1.0000x reference)
//
#include <hip/hip_runtime.h>

typedef unsigned int u32;
typedef unsigned short u16;
typedef unsigned long long u64;
typedef __attribute__((ext_vector_type(8))) short short8;
typedef __attribute__((ext_vector_type(4))) float f32x4;
typedef __attribute__((ext_vector_type(4))) u32 u32x4;
typedef __attribute__((ext_vector_type(2))) u32 u32x2;

#define SEQ 512
#define BATCH 32
#define DIM 1024
#define NB 128   // persistent blocks in recurrent kernel

// workspace layout (bytes)
#define OFF_XT    0ull                  // bf16 [16384][1024] Xt  (dead after k_gemm)
                                        // -> REUSED as tagged h: u32 [2][32768] (256KB)
#define OFF_UBT   33554432ull           // bf16 [4096][1024]   U^T concat (k_gemm B)
#define OFF_WG2   41943040ull           // bf16 [128 blk][32 ks][32 rr][32 kk] K-major tiled W
#define OFF_XPROJ 50331648ull           // bf16 [512][32][4096]
#define OFF_BIAS  184680448ull          // f32  [4096]

__device__ __forceinline__ float bf2f(u16 u) {
  union { u32 u; float f; } v; v.u = ((u32)u) << 16; return v.f;
}
__device__ __forceinline__ u16 f2bf(float f) {
  union { float f; u32 u; } v; v.f = f;
  u32 r = v.u + 0x7FFFu + ((v.u >> 16) & 1u);
  return (u16)(r >> 16);
}
// tanh(x) = 1 - 2/(1+e^{2x}) : exact identity, __expf-based
__device__ __forceinline__ float tanh_fast(float x) {
  return 1.f - 2.f / (1.f + __expf(2.f * x));
}
__device__ __forceinline__ void gload_lds16(const u16* g, u16* l) {
  __builtin_amdgcn_global_load_lds(
      (const __attribute__((address_space(1))) u32*)g,
      (__attribute__((address_space(3))) u32*)l, 16, 0, 0);
}

// ---------------- init: concat bias ---------------------------------------
__global__ void k_init(float* biasc, const float* bi, const float* bfv,
                       const float* bo, const float* bg) {
  int e = blockIdx.x * 256 + threadIdx.x;
  if (e < 4096) {
    int g = e >> 10, c = e & 1023;
    const float* p = (g == 0) ? bi : (g == 1) ? bfv : (g == 2) ? bo : bg;
    biasc[e] = p[c];
  }
}

// ---------------- zero the tagged h double-buffer (runs AFTER k_gemm) -----
// zeros = (tag 0 | h 0.0bf16) == exactly the step-0 initial state. 64 blocks.
__global__ void k_zero(u32x4* p) {
  p[blockIdx.x * 256 + threadIdx.x] = (u32x4){0u, 0u, 0u, 0u};
}

// ---------------- transpose-cast the 8 weight matrices --------------------
__global__ void k_prep_w(const float* Ui, const float* Wi, const float* Uf,
                         const float* Wf, const float* Uo, const float* Wo,
                         const float* Ug, const float* Wg, u16* Ubt, u16* Wg2) {
  __shared__ float tile[64][65];
  int bx = blockIdx.x;
  int mi = bx >> 8;               // matrix 0..7 (Ui,Wi,Uf,Wf,Uo,Wo,Ug,Wg)
  int tt = bx & 255;
  int tr = tt >> 4, tc = tt & 15; // 16x16 grid of 64x64 tiles
  const float* src;
  switch (mi) {
    case 0: src = Ui; break; case 1: src = Wi; break;
    case 2: src = Uf; break; case 3: src = Wf; break;
    case 4: src = Uo; break; case 5: src = Wo; break;
    case 6: src = Ug; break; default: src = Wg; break;
  }
  int g = mi >> 1;
  int d0 = tr * 64, c0 = tc * 64;
  int ty = threadIdx.x >> 6, tx = threadIdx.x & 63;
#pragma unroll
  for (int i = 0; i < 16; ++i) {
    int r = i * 4 + ty;
    tile[r][tx] = src[(size_t)(d0 + r) * 1024 + c0 + tx];
  }
  __syncthreads();
  if (mi & 1) {
#pragma unroll
    for (int i = 0; i < 16; ++i) {
      int cc = i * 4 + ty;
      int c_full = c0 + cc;
      int k = d0 + tx;
      int blk = c_full >> 3;
      int rr = (g << 3) | (c_full & 7);
      Wg2[(size_t)blk * 32768 + ((k >> 5) << 10) + rr * 32 + (k & 31)] =
          f2bf(tile[tx][cc]);
    }
  } else {
#pragma unroll
    for (int i = 0; i < 16; ++i) {
      int cc = i * 4 + ty;
      Ubt[(size_t)((g << 10) + c0 + cc) * 1024 + d0 + tx] = f2bf(tile[tx][cc]);
    }
  }
}

// ---------------- transpose-cast X: Xt[s*32+b][d] = X[b][s][d] ------------
__global__ void k_prep_x(const float* __restrict__ X, u16* __restrict__ Xt) {
  int idx = blockIdx.x * 256 + threadIdx.x;
  int m = idx >> 8, d4 = (idx & 255) << 2;
  int s = m >> 5, b = m & 31;
  const float4* p = (const float4*)(X + (size_t)(b * SEQ + s) * DIM + d4);
  float4 v = *p;
  u16 o[4] = { f2bf(v.x), f2bf(v.y), f2bf(v.z), f2bf(v.w) };
  *(ushort4*)(Xt + (size_t)m * DIM + d4) = *(ushort4*)o;
}

// ---------------- phase 1 GEMM: xproj = Xt @ U + bias  (m97 structure) ----
__global__ __launch_bounds__(256) void k_gemm(const u16* __restrict__ Xt,
                                              const u16* __restrict__ Ubt,
                                              const float* __restrict__ biasc,
                                              u16* __restrict__ xproj) {
  __shared__ u16 As[128 * 32];
  __shared__ u16 Bs[128 * 32];
  int tid = threadIdx.x;
  int w = tid >> 6, l = tid & 63;
  int n0 = blockIdx.x * 128, m0 = blockIdx.y * 128;
  int wm = w >> 1, wn = w & 1;
  int lrow = l & 15, lq = l >> 4;
  f32x4 acc[4][4] = {};
  for (int kt = 0; kt < 32; ++kt) {
    int k0 = kt * 32;
    __syncthreads();
#pragma unroll
    for (int is = 0; is < 2; ++is) {
      int c = is * 256 + w * 64 + l;
      int row = c >> 2, kg = c & 3;
      gload_lds16(Xt + (size_t)(m0 + row) * 1024 + k0 + kg * 8, As + c * 8);
      gload_lds16(Ubt + (size_t)(n0 + row) * 1024 + k0 + kg * 8, Bs + c * 8);
    }
    __syncthreads();
    short8 af[4], bfr[4];
#pragma unroll
    for (int mt = 0; mt < 4; ++mt)
      af[mt] = *(const short8*)(As + (wm * 64 + mt * 16 + lrow) * 32 + lq * 8);
#pragma unroll
    for (int nt = 0; nt < 4; ++nt)
      bfr[nt] = *(const short8*)(Bs + (wn * 64 + nt * 16 + lrow) * 32 + lq * 8);
#pragma unroll
    for (int mt = 0; mt < 4; ++mt)
#pragma unroll
      for (int nt = 0; nt < 4; ++nt)
        acc[mt][nt] = __builtin_amdgcn_mfma_f32_16x16x32_bf16(
            af[mt], bfr[nt], acc[mt][nt], 0, 0, 0);
  }
#pragma unroll
  for (int nt = 0; nt < 4; ++nt) {
    int col = n0 + wn * 64 + nt * 16 + lrow;
    float bv = biasc[col];
#pragma unroll
    for (int mt = 0; mt < 4; ++mt) {
      int rbase = m0 + wm * 64 + mt * 16 + lq * 4;
#pragma unroll
      for (int r = 0; r < 4; ++r)
        xproj[(size_t)(rbase + r) * 4096 + col] = f2bf(acc[mt][nt][r] + bv);
    }
  }
}

// ---------------- phase 2: persistent recurrent kernel --------------------
// R5: FLAG-FREE tagged-word h exchange.
//   Producer: one relaxed-agent atomic u32 store per h element:
//             (tag=s+1)<<16 | bf16(h). Fire-and-forget; no ack, no flag.
//   Consumer: 32x global_load_dwordx4 sc0 sc1 (LLC-coherent, lane-contiguous,
//             coalesced), accept a word iff tag==s; stale quads retried via
//             __hip_atomic_load. First load round IS the poll.
// Safety: block stores tag s+1 only after consuming all tags s; overwrite of
// a parity buffer (tag s+2) requires all tags s+1 observed -> all blocks done
// consuming tags s. Tag equality can therefore never accept a wrong step.
__global__ __launch_bounds__(256, 1) void k_rec(const u16* __restrict__ Wg2,
                                                const u16* __restrict__ xproj,
                                                u32* hbt, float* out) {
  __shared__ u16 Ws[32 * 1024];     // 64KB, staged once
  __shared__ u16 Hs[32 * 1024];     // 64KB packed bf16 h, rebuilt per step
  __shared__ u16 XPs[32 * 32];      // 2KB x_proj slice (prefetched)
  __shared__ float zbuf[32][33];    // 4.2KB z tile
  int tid = threadIdx.x;
  int w = tid >> 6, l = tid & 63;
  int blk = blockIdx.x;
  int lrow = l & 15, lq = l >> 4;
  // stage W slice once: linear 64KB copy (already in per-block tiled order)
#pragma unroll
  for (int it = 0; it < 16; ++it) {
    int c = it * 256 + w * 64 + l;
    gload_lds16(Wg2 + (size_t)blk * 32768 + c * 8, Ws + c * 8);
  }
  // prefetch xproj slice for s=0
  if (w < 2) {
    int c2 = w * 64 + l;
    int b = c2 >> 2, g = c2 & 3;
    gload_lds16(xproj + (size_t)b * 4096 + (g << 10) + (blk << 3), XPs + c2 * 8);
  }
  float c_reg = 0.f;
  int eb = tid >> 3, ec = tid & 7;  // epilogue: thread owns (batch eb, hcol ec)
  int mt = w >> 1, nt = w & 1;      // wave tile assignment
  const u16* ap0 = Hs + (mt * 16 + lrow) * 32 + lq * 8;
  const u16* bp0 = Ws + (nt * 16 + lrow) * 32 + lq * 8;
  // tagged h store address (K-major tiled word index, d = blk*8+ec)
  u32* hst = hbt + ((blk >> 2) << 10) + eb * 32 + ((blk & 3) << 3) + ec;
  float* out_base = out + (size_t)eb * SEQ * DIM + (blk << 3) + ec;
  __syncthreads();                   // W + XPs staged

  for (int s = 0; s < SEQ; ++s) {
    const u32* hsrc = hbt + (size_t)(s & 1) * 32768;
    u32 T = (u32)s << 16;

    // ---- issue all 32 coherent x4 loads (lane-contiguous => coalesced) ----
    u32x4 q[32];
#pragma unroll
    for (int qd = 0; qd < 32; ++qd) {
      asm volatile("global_load_dwordx4 %0, %1, off sc0 sc1"
                   : "=v"(q[qd])
                   : "v"(hsrc + qd * 1024 + tid * 4));
    }
    asm volatile("s_waitcnt vmcnt(0)" ::: "memory");
    __builtin_amdgcn_sched_barrier(0);

    // ---- verify tags per quad, retry stale, pack low16s -> Hs -------------
#pragma unroll
    for (int qd = 0; qd < 32; ++qd) {
      const u32* p = hsrc + qd * 1024 + tid * 4;
      int guard = 0;
      for (;;) {
        u32 m = (q[qd].x ^ T) | (q[qd].y ^ T) | (q[qd].z ^ T) | (q[qd].w ^ T);
        if (!(m & 0xFFFF0000u)) break;
        if (++guard > 20000000) break;   // anti-hang bailout
        q[qd].x = __hip_atomic_load(p + 0, __ATOMIC_RELAXED,
                                    __HIP_MEMORY_SCOPE_AGENT);
        q[qd].y = __hip_atomic_load(p + 1, __ATOMIC_RELAXED,
                                    __HIP_MEMORY_SCOPE_AGENT);
        q[qd].z = __hip_atomic_load(p + 2, __ATOMIC_RELAXED,
                                    __HIP_MEMORY_SCOPE_AGENT);
        q[qd].w = __hip_atomic_load(p + 3, __ATOMIC_RELAXED,
                                    __HIP_MEMORY_SCOPE_AGENT);
      }
      // dst dword = (lo16(B)<<16)|lo16(A): v_perm(src0=B, src1=A, 0x05040100)
      u32 p0 = __builtin_amdgcn_perm(q[qd].y, q[qd].x, 0x05040100u);
      u32 p1 = __builtin_amdgcn_perm(q[qd].w, q[qd].z, 0x05040100u);
      u32x2 pk = { p0, p1 };
      *(u32x2*)((char*)Hs + qd * 2048 + tid * 8) = pk;   // ds_write_b64
    }
    __syncthreads();                 // SYNC-S: Hs staged (drains all vmcnt)

    // ---- z = h_prev @ W_slice : wave (mt,nt) computes 16x16 tile ----------
    f32x4 acc0 = { 0.f, 0.f, 0.f, 0.f };
    f32x4 acc1 = { 0.f, 0.f, 0.f, 0.f };
#pragma unroll
    for (int ks = 0; ks < 16; ++ks) {
      short8 a0 = *(const short8*)(ap0 + (2 * ks) * 1024);
      short8 b0 = *(const short8*)(bp0 + (2 * ks) * 1024);
      short8 a1 = *(const short8*)(ap0 + (2 * ks + 1) * 1024);
      short8 b1 = *(const short8*)(bp0 + (2 * ks + 1) * 1024);
      acc0 = __builtin_amdgcn_mfma_f32_16x16x32_bf16(a0, b0, acc0, 0, 0, 0);
      acc1 = __builtin_amdgcn_mfma_f32_16x16x32_bf16(a1, b1, acc1, 0, 0, 0);
    }
    f32x4 acc = acc0 + acc1;
    {
      int col = nt * 16 + lrow;
      int rb = mt * 16 + lq * 4;
#pragma unroll
      for (int r = 0; r < 4; ++r) zbuf[rb + r][col] = acc[r];
    }
    __syncthreads();                 // SYNC-A: zbuf ready

    // gates: zbuf cols 0-7=i, 8-15=f, 16-23=o, 24-31=g
    float zi = zbuf[eb][ec]      + bf2f(XPs[eb * 32 + ec]);
    float zf = zbuf[eb][8 + ec]  + bf2f(XPs[eb * 32 + 8 + ec]);
    float zo = zbuf[eb][16 + ec] + bf2f(XPs[eb * 32 + 16 + ec]);
    float zg = zbuf[eb][24 + ec] + bf2f(XPs[eb * 32 + 24 + ec]);
    float ig = 1.f / (1.f + __expf(-zi));
    float fg = 1.f / (1.f + __expf(-zf));
    float og = 1.f / (1.f + __expf(-zo));
    float gg = tanh_fast(zg);
    c_reg = 1.f / (1.f + __expf(-(fg * c_reg + ig * gg)));  // nonstandard cell
    float h = tanh_fast(c_reg) * og;

    // tagged fire-and-forget h store (tag s+1 | bf16 h) — no ack, no flag
    u32 hw = ((u32)(s + 1) << 16) | (u32)f2bf(h);
    __hip_atomic_store(hst + (size_t)((s + 1) & 1) * 32768, hw,
                       __ATOMIC_RELAXED, __HIP_MEMORY_SCOPE_AGENT);

    // xproj prefetch for next step (retires during next staging window)
    {
      int sp = (s + 1 < SEQ) ? s + 1 : s;
      if (w < 2) {
        int c2 = w * 64 + l;
        int b = c2 >> 2, g = c2 & 3;
        gload_lds16(xproj + (size_t)(sp * 32 + b) * 4096 + (g << 10) + (blk << 3),
                    XPs + c2 * 8);
      }
    }
    // out-store: ack drains in next staging window's shadow
    __builtin_nontemporal_store(h, out_base + (size_t)s * DIM);
  }
}

// ---------------------------------------------------------------------------
extern "C" void kernel_launch(void* const* d_in, const int* in_sizes, int n_in,
                              void* d_out, int out_size, void* d_ws,
                              size_t ws_size, hipStream_t stream) {
  const float* X   = (const float*)d_in[0];
  const float* Ui  = (const float*)d_in[1];
  const float* Wi  = (const float*)d_in[2];
  const float* Uf  = (const float*)d_in[3];
  const float* Wf  = (const float*)d_in[4];
  const float* Uo  = (const float*)d_in[5];
  const float* Wo  = (const float*)d_in[6];
  const float* Ug  = (const float*)d_in[7];
  const float* Wg  = (const float*)d_in[8];
  const float* bi  = (const float*)d_in[9];
  const float* bfv = (const float*)d_in[10];
  const float* bo  = (const float*)d_in[11];
  const float* bg  = (const float*)d_in[12];
  char* ws = (char*)d_ws;
  u16* Xt      = (u16*)(ws + OFF_XT);
  u32* hbt     = (u32*)(ws + OFF_XT);      // tagged h reuses dead Xt region
  u16* Ubt     = (u16*)(ws + OFF_UBT);
  u16* Wg2     = (u16*)(ws + OFF_WG2);
  u16* xproj   = (u16*)(ws + OFF_XPROJ);
  float* biasc = (float*)(ws + OFF_BIAS);
  float* out   = (float*)d_out;

  k_init<<<16, 256, 0, stream>>>(biasc, bi, bfv, bo, bg);
  k_prep_w<<<2048, 256, 0, stream>>>(Ui, Wi, Uf, Wf, Uo, Wo, Ug, Wg, Ubt, Wg2);
  k_prep_x<<<16384, 256, 0, stream>>>(X, Xt);
  k_gemm<<<dim3(32, 128), 256, 0, stream>>>(Xt, Ubt, biasc, xproj);
  k_zero<<<64, 256, 0, stream>>>((u32x4*)hbt);   // after gemm: Xt is dead
  k_rec<<<NB, 256, 0, stream>>>(Wg2, xproj, hbt, out);
}

// Round 3
// 3125.469 us; speedup vs baseline: 2.4730x; 2.4730x over previous
//
#include <hip/hip_runtime.h>

typedef unsigned int u32;
typedef unsigned short u16;
typedef unsigned long long u64;
typedef __attribute__((ext_vector_type(8))) short short8;
typedef __attribute__((ext_vector_type(4))) float f32x4;
typedef __attribute__((ext_vector_type(4))) u32 u32x4;
typedef __attribute__((ext_vector_type(2))) u32 u32x2;

#define SEQ 512
#define BATCH 32
#define DIM 1024
#define NB 128   // persistent blocks in recurrent kernel

// workspace layout (bytes)
#define OFF_XT    0ull                  // bf16 [16384][1024] Xt  (dead after k_gemm)
                                        // -> REUSED as tagged h: u32 [2][32768] (256KB)
#define OFF_UBT   33554432ull           // bf16 [4096][1024]   U^T concat (k_gemm B)
#define OFF_WG2   41943040ull           // bf16 [128 blk][32 ks][32 rr][32 kk] K-major tiled W
#define OFF_XPROJ 50331648ull           // bf16 [512][32][4096]
#define OFF_BIAS  184680448ull          // f32  [4096]

__device__ __forceinline__ float bf2f(u16 u) {
  union { u32 u; float f; } v; v.u = ((u32)u) << 16; return v.f;
}
__device__ __forceinline__ u16 f2bf(float f) {
  union { float f; u32 u; } v; v.f = f;
  u32 r = v.u + 0x7FFFu + ((v.u >> 16) & 1u);
  return (u16)(r >> 16);
}
// tanh(x) = 1 - 2/(1+e^{2x}) : exact identity, __expf-based
__device__ __forceinline__ float tanh_fast(float x) {
  return 1.f - 2.f / (1.f + __expf(2.f * x));
}
__device__ __forceinline__ void gload_lds16(const u16* g, u16* l) {
  __builtin_amdgcn_global_load_lds(
      (const __attribute__((address_space(1))) u32*)g,
      (__attribute__((address_space(3))) u32*)l, 16, 0, 0);
}

// ---------------- init: concat bias ---------------------------------------
__global__ void k_init(float* biasc, const float* bi, const float* bfv,
                       const float* bo, const float* bg) {
  int e = blockIdx.x * 256 + threadIdx.x;
  if (e < 4096) {
    int g = e >> 10, c = e & 1023;
    const float* p = (g == 0) ? bi : (g == 1) ? bfv : (g == 2) ? bo : bg;
    biasc[e] = p[c];
  }
}

// ---------------- zero the tagged h double-buffer (runs AFTER k_gemm) -----
// zeros = (tag 0 | h 0.0bf16) == exactly the step-0 initial state. 64 blocks.
__global__ void k_zero(u32x4* p) {
  p[blockIdx.x * 256 + threadIdx.x] = (u32x4){0u, 0u, 0u, 0u};
}

// ---------------- transpose-cast the 8 weight matrices --------------------
__global__ void k_prep_w(const float* Ui, const float* Wi, const float* Uf,
                         const float* Wf, const float* Uo, const float* Wo,
                         const float* Ug, const float* Wg, u16* Ubt, u16* Wg2) {
  __shared__ float tile[64][65];
  int bx = blockIdx.x;
  int mi = bx >> 8;               // matrix 0..7 (Ui,Wi,Uf,Wf,Uo,Wo,Ug,Wg)
  int tt = bx & 255;
  int tr = tt >> 4, tc = tt & 15; // 16x16 grid of 64x64 tiles
  const float* src;
  switch (mi) {
    case 0: src = Ui; break; case 1: src = Wi; break;
    case 2: src = Uf; break; case 3: src = Wf; break;
    case 4: src = Uo; break; case 5: src = Wo; break;
    case 6: src = Ug; break; default: src = Wg; break;
  }
  int g = mi >> 1;
  int d0 = tr * 64, c0 = tc * 64;
  int ty = threadIdx.x >> 6, tx = threadIdx.x & 63;
#pragma unroll
  for (int i = 0; i < 16; ++i) {
    int r = i * 4 + ty;
    tile[r][tx] = src[(size_t)(d0 + r) * 1024 + c0 + tx];
  }
  __syncthreads();
  if (mi & 1) {
#pragma unroll
    for (int i = 0; i < 16; ++i) {
      int cc = i * 4 + ty;
      int c_full = c0 + cc;
      int k = d0 + tx;
      int blk = c_full >> 3;
      int rr = (g << 3) | (c_full & 7);
      Wg2[(size_t)blk * 32768 + ((k >> 5) << 10) + rr * 32 + (k & 31)] =
          f2bf(tile[tx][cc]);
    }
  } else {
#pragma unroll
    for (int i = 0; i < 16; ++i) {
      int cc = i * 4 + ty;
      Ubt[(size_t)((g << 10) + c0 + cc) * 1024 + d0 + tx] = f2bf(tile[tx][cc]);
    }
  }
}

// ---------------- transpose-cast X: Xt[s*32+b][d] = X[b][s][d] ------------
__global__ void k_prep_x(const float* __restrict__ X, u16* __restrict__ Xt) {
  int idx = blockIdx.x * 256 + threadIdx.x;
  int m = idx >> 8, d4 = (idx & 255) << 2;
  int s = m >> 5, b = m & 31;
  const float4* p = (const float4*)(X + (size_t)(b * SEQ + s) * DIM + d4);
  float4 v = *p;
  u16 o[4] = { f2bf(v.x), f2bf(v.y), f2bf(v.z), f2bf(v.w) };
  *(ushort4*)(Xt + (size_t)m * DIM + d4) = *(ushort4*)o;
}

// ---------------- phase 1 GEMM: xproj = Xt @ U + bias  (m97 structure) ----
__global__ __launch_bounds__(256) void k_gemm(const u16* __restrict__ Xt,
                                              const u16* __restrict__ Ubt,
                                              const float* __restrict__ biasc,
                                              u16* __restrict__ xproj) {
  __shared__ u16 As[128 * 32];
  __shared__ u16 Bs[128 * 32];
  int tid = threadIdx.x;
  int w = tid >> 6, l = tid & 63;
  int n0 = blockIdx.x * 128, m0 = blockIdx.y * 128;
  int wm = w >> 1, wn = w & 1;
  int lrow = l & 15, lq = l >> 4;
  f32x4 acc[4][4] = {};
  for (int kt = 0; kt < 32; ++kt) {
    int k0 = kt * 32;
    __syncthreads();
#pragma unroll
    for (int is = 0; is < 2; ++is) {
      int c = is * 256 + w * 64 + l;
      int row = c >> 2, kg = c & 3;
      gload_lds16(Xt + (size_t)(m0 + row) * 1024 + k0 + kg * 8, As + c * 8);
      gload_lds16(Ubt + (size_t)(n0 + row) * 1024 + k0 + kg * 8, Bs + c * 8);
    }
    __syncthreads();
    short8 af[4], bfr[4];
#pragma unroll
    for (int mt = 0; mt < 4; ++mt)
      af[mt] = *(const short8*)(As + (wm * 64 + mt * 16 + lrow) * 32 + lq * 8);
#pragma unroll
    for (int nt = 0; nt < 4; ++nt)
      bfr[nt] = *(const short8*)(Bs + (wn * 64 + nt * 16 + lrow) * 32 + lq * 8);
#pragma unroll
    for (int mt = 0; mt < 4; ++mt)
#pragma unroll
      for (int nt = 0; nt < 4; ++nt)
        acc[mt][nt] = __builtin_amdgcn_mfma_f32_16x16x32_bf16(
            af[mt], bfr[nt], acc[mt][nt], 0, 0, 0);
  }
#pragma unroll
  for (int nt = 0; nt < 4; ++nt) {
    int col = n0 + wn * 64 + nt * 16 + lrow;
    float bv = biasc[col];
#pragma unroll
    for (int mt = 0; mt < 4; ++mt) {
      int rbase = m0 + wm * 64 + mt * 16 + lq * 4;
#pragma unroll
      for (int r = 0; r < 4; ++r)
        xproj[(size_t)(rbase + r) * 4096 + col] = f2bf(acc[mt][nt][r] + bv);
    }
  }
}

// ---------------- phase 2: persistent recurrent kernel --------------------
// R6: tagged-word h exchange (R5 protocol — hardware-verified safe) with a
// BULK-RETRY consumer schedule:
//   - issue all 32 dwordx4 loads, ONE vmcnt(0), build 32-bit stale mask
//   - wave-uniform retry loop: s_sleep backoff, re-issue ONLY stale quads
//     (statically unrolled + exec-predicated), one vmcnt(0) per round
//   - no per-quad serial spinning, no scalar atomic hammering (R5's killers)
// Producer side stays fire-and-forget: one relaxed agent store per h word,
// (tag s+1)<<16 | bf16(h). No ack wait, no flag, no poll.
// Safety induction (verified by R5 pass): a parity buffer readable at target
// s holds only tags s or s-2; tag-equality acceptance is exact.
__global__ __launch_bounds__(256, 1) void k_rec(const u16* __restrict__ Wg2,
                                                const u16* __restrict__ xproj,
                                                u32* hbt, float* out) {
  __shared__ u16 Ws[32 * 1024];     // 64KB, staged once
  __shared__ u16 Hs[32 * 1024];     // 64KB packed bf16 h, rebuilt per step
  __shared__ u16 XPs[2][1024];      // 2x2KB x_proj slice, double-buffered
  __shared__ float zbuf[32][33];    // 4.2KB z tile
  int tid = threadIdx.x;
  int w = tid >> 6, l = tid & 63;
  int blk = blockIdx.x;
  int lrow = l & 15, lq = l >> 4;
  // stage W slice once: linear 64KB copy (already in per-block tiled order)
#pragma unroll
  for (int it = 0; it < 16; ++it) {
    int c = it * 256 + w * 64 + l;
    gload_lds16(Wg2 + (size_t)blk * 32768 + c * 8, Ws + c * 8);
  }
  // prefetch xproj slice for s=0 into parity-0 buffer
  if (w < 2) {
    int c2 = w * 64 + l;
    int b = c2 >> 2, g = c2 & 3;
    gload_lds16(xproj + (size_t)b * 4096 + (g << 10) + (blk << 3),
                XPs[0] + c2 * 8);
  }
  float c_reg = 0.f;
  int eb = tid >> 3, ec = tid & 7;  // epilogue: thread owns (batch eb, hcol ec)
  int mt = w >> 1, nt = w & 1;      // wave tile assignment
  const u16* ap0 = Hs + (mt * 16 + lrow) * 32 + lq * 8;
  const u16* bp0 = Ws + (nt * 16 + lrow) * 32 + lq * 8;
  // tagged h store address (K-major tiled word index, d = blk*8+ec)
  u32* hst = hbt + ((blk >> 2) << 10) + eb * 32 + ((blk & 3) << 3) + ec;
  float* out_base = out + (size_t)eb * SEQ * DIM + (blk << 3) + ec;
  __syncthreads();                   // W + XPs[0] staged

  for (int s = 0; s < SEQ; ++s) {
    const u32* hsrc = hbt + (size_t)(s & 1) * 32768;
    u32 T = (u32)s << 16;

    // ---- issue all 32 coherent x4 loads (lane-contiguous => coalesced) ----
    u32x4 q[32];
#pragma unroll
    for (int qd = 0; qd < 32; ++qd) {
      asm volatile("global_load_dwordx4 %0, %1, off sc0 sc1"
                   : "=v"(q[qd])
                   : "v"(hsrc + qd * 1024 + tid * 4));
    }
    asm volatile("s_waitcnt vmcnt(0)" ::: "memory");
    __builtin_amdgcn_sched_barrier(0);

    // ---- bulk verify + bulk retry (wave-uniform exit) ---------------------
    {
      int guard = 0;
      for (;;) {
        u32 stale = 0u;
#pragma unroll
        for (int qd = 0; qd < 32; ++qd) {
          u32 m = ((q[qd].x ^ T) | (q[qd].y ^ T) | (q[qd].z ^ T) |
                   (q[qd].w ^ T)) & 0xFFFF0000u;
          stale |= m ? (1u << qd) : 0u;
        }
        if (!__any((int)(stale != 0u))) break;
        if (++guard > 2000000) break;    // anti-hang bailout
        __builtin_amdgcn_s_sleep(2);
        // re-issue ONLY stale quads; exec-predicated, statically unrolled
#pragma unroll
        for (int qd = 0; qd < 32; ++qd) {
          if (stale & (1u << qd)) {
            asm volatile("global_load_dwordx4 %0, %1, off sc0 sc1"
                         : "=v"(q[qd])
                         : "v"(hsrc + qd * 1024 + tid * 4));
          }
        }
        asm volatile("s_waitcnt vmcnt(0)" ::: "memory");
        __builtin_amdgcn_sched_barrier(0);
      }
    }

    // ---- pack low16s -> Hs ------------------------------------------------
#pragma unroll
    for (int qd = 0; qd < 32; ++qd) {
      // dst dword = (lo16(B)<<16)|lo16(A): v_perm(src0=B, src1=A, 0x05040100)
      u32 p0 = __builtin_amdgcn_perm(q[qd].y, q[qd].x, 0x05040100u);
      u32 p1 = __builtin_amdgcn_perm(q[qd].w, q[qd].z, 0x05040100u);
      u32x2 pk = { p0, p1 };
      *(u32x2*)((char*)Hs + qd * 2048 + tid * 8) = pk;   // ds_write_b64
    }
    __syncthreads();                 // SYNC-S: Hs staged (drains vm+lgkm)

    // ---- z = h_prev @ W_slice : wave (mt,nt) computes 16x16 tile ----------
    f32x4 acc0 = { 0.f, 0.f, 0.f, 0.f };
    f32x4 acc1 = { 0.f, 0.f, 0.f, 0.f };
#pragma unroll
    for (int ks = 0; ks < 16; ++ks) {
      short8 a0 = *(const short8*)(ap0 + (2 * ks) * 1024);
      short8 b0 = *(const short8*)(bp0 + (2 * ks) * 1024);
      short8 a1 = *(const short8*)(ap0 + (2 * ks + 1) * 1024);
      short8 b1 = *(const short8*)(bp0 + (2 * ks + 1) * 1024);
      acc0 = __builtin_amdgcn_mfma_f32_16x16x32_bf16(a0, b0, acc0, 0, 0, 0);
      acc1 = __builtin_amdgcn_mfma_f32_16x16x32_bf16(a1, b1, acc1, 0, 0, 0);
    }
    f32x4 acc = acc0 + acc1;
    {
      int col = nt * 16 + lrow;
      int rb = mt * 16 + lq * 4;
#pragma unroll
      for (int r = 0; r < 4; ++r) zbuf[rb + r][col] = acc[r];
    }
    __syncthreads();                 // SYNC-A: zbuf ready

    // gates: zbuf cols 0-7=i, 8-15=f, 16-23=o, 24-31=g
    const u16* xp = XPs[s & 1];
    float zi = zbuf[eb][ec]      + bf2f(xp[eb * 32 + ec]);
    float zf = zbuf[eb][8 + ec]  + bf2f(xp[eb * 32 + 8 + ec]);
    float zo = zbuf[eb][16 + ec] + bf2f(xp[eb * 32 + 16 + ec]);
    float zg = zbuf[eb][24 + ec] + bf2f(xp[eb * 32 + 24 + ec]);
    float ig = 1.f / (1.f + __expf(-zi));
    float fg = 1.f / (1.f + __expf(-zf));
    float og = 1.f / (1.f + __expf(-zo));
    float gg = tanh_fast(zg);
    c_reg = 1.f / (1.f + __expf(-(fg * c_reg + ig * gg)));  // nonstandard cell
    float h = tanh_fast(c_reg) * og;

    // tagged fire-and-forget h store (tag s+1 | bf16 h) — no ack, no flag
    u32 hw = ((u32)(s + 1) << 16) | (u32)f2bf(h);
    __hip_atomic_store(hst + (size_t)((s + 1) & 1) * 32768, hw,
                       __ATOMIC_RELAXED, __HIP_MEMORY_SCOPE_AGENT);

    // xproj prefetch for next step into the OTHER XPs parity buffer
    {
      int sp = (s + 1 < SEQ) ? s + 1 : s;
      if (w < 2) {
        int c2 = w * 64 + l;
        int b = c2 >> 2, g = c2 & 3;
        gload_lds16(xproj + (size_t)(sp * 32 + b) * 4096 + (g << 10) + (blk << 3),
                    XPs[(s + 1) & 1] + c2 * 8);
      }
    }
    // out-store: ack drains in next staging window's shadow
    __builtin_nontemporal_store(h, out_base + (size_t)s * DIM);
  }
}

// ---------------------------------------------------------------------------
extern "C" void kernel_launch(void* const* d_in, const int* in_sizes, int n_in,
                              void* d_out, int out_size, void* d_ws,
                              size_t ws_size, hipStream_t stream) {
  const float* X   = (const float*)d_in[0];
  const float* Ui  = (const float*)d_in[1];
  const float* Wi  = (const float*)d_in[2];
  const float* Uf  = (const float*)d_in[3];
  const float* Wf  = (const float*)d_in[4];
  const float* Uo  = (const float*)d_in[5];
  const float* Wo  = (const float*)d_in[6];
  const float* Ug  = (const float*)d_in[7];
  const float* Wg  = (const float*)d_in[8];
  const float* bi  = (const float*)d_in[9];
  const float* bfv = (const float*)d_in[10];
  const float* bo  = (const float*)d_in[11];
  const float* bg  = (const float*)d_in[12];
  char* ws = (char*)d_ws;
  u16* Xt      = (u16*)(ws + OFF_XT);
  u32* hbt     = (u32*)(ws + OFF_XT);      // tagged h reuses dead Xt region
  u16* Ubt     = (u16*)(ws + OFF_UBT);
  u16* Wg2     = (u16*)(ws + OFF_WG2);
  u16* xproj   = (u16*)(ws + OFF_XPROJ);
  float* biasc = (float*)(ws + OFF_BIAS);
  float* out   = (float*)d_out;

  k_init<<<16, 256, 0, stream>>>(biasc, bi, bfv, bo, bg);
  k_prep_w<<<2048, 256, 0, stream>>>(Ui, Wi, Uf, Wf, Uo, Wo, Ug, Wg, Ubt, Wg2);
  k_prep_x<<<16384, 256, 0, stream>>>(X, Xt);
  k_gemm<<<dim3(32, 128), 256, 0, stream>>>(Xt, Ubt, biasc, xproj);
  k_zero<<<64, 256, 0, stream>>>((u32x4*)hbt);   // after gemm: Xt is dead
  k_rec<<<NB, 256, 0, stream>>>(Wg2, xproj, hbt, out);
}

// Round 4
// 2688.305 us; speedup vs baseline: 2.8751x; 1.1626x over previous
//
#include <hip/hip_runtime.h>

typedef unsigned int u32;
typedef unsigned short u16;
typedef unsigned long long u64;
typedef __attribute__((ext_vector_type(8))) short short8;
typedef __attribute__((ext_vector_type(4))) float f32x4;

#define SEQ 512
#define BATCH 32
#define DIM 1024
#define NB 128   // persistent blocks in recurrent kernel

// workspace layout (bytes)
#define OFF_XT    0ull                  // bf16 [16384][1024]  (row m = s*32+b)
#define OFF_UBT   33554432ull           // bf16 [4096][1024]   U^T concat (k_gemm B)
#define OFF_WG2   41943040ull           // bf16 [128 blk][32 ks][32 rr][32 kk] K-major tiled W
#define OFF_XPROJ 50331648ull           // bf16 [512][32][4096]
#define OFF_HBUF  184549376ull          // bf16 [2][32768] K-major tiled h
#define OFF_BIAS  184680448ull          // f32  [4096]
#define OFF_SYNC  184696832ull          // u32 flags[2 group][128 blk][16] (64B-padded)

__device__ __forceinline__ float bf2f(u16 u) {
  union { u32 u; float f; } v; v.u = ((u32)u) << 16; return v.f;
}
__device__ __forceinline__ u16 f2bf(float f) {
  union { float f; u32 u; } v; v.f = f;
  u32 r = v.u + 0x7FFFu + ((v.u >> 16) & 1u);
  return (u16)(r >> 16);
}
// tanh(x) = 1 - 2/(1+e^{2x}) : exact identity, __expf-based
__device__ __forceinline__ float tanh_fast(float x) {
  return 1.f - 2.f / (1.f + __expf(2.f * x));
}
__device__ __forceinline__ void gload_lds16(const u16* g, u16* l) {
  __builtin_amdgcn_global_load_lds(
      (const __attribute__((address_space(1))) u32*)g,
      (__attribute__((address_space(3))) u32*)l, 16, 0, 0);
}
// LLC-coherent LDS-DMA: aux=17 = SC0|SC1 -> bypass L1+L2, read at LLC
__device__ __forceinline__ void gload_lds16_coh(const u16* g, u16* l) {
  __builtin_amdgcn_global_load_lds(
      (const __attribute__((address_space(1))) u32*)g,
      (__attribute__((address_space(3))) u32*)l, 16, 0, 17);
}

// 2-wave sync inside one half (waves wv=0,1 of group g) via LDS flags.
// Monotone epoch counter; lane 0 of each wave publishes, all lanes spin.
__device__ __forceinline__ void half_sync(volatile u32* hsf, int g, int wv,
                                          u32 ep) {
  asm volatile("s_waitcnt lgkmcnt(0)" ::: "memory");   // prior ds_writes done
  if ((threadIdx.x & 63) == 0) hsf[g * 2 + wv] = ep;
  asm volatile("s_waitcnt lgkmcnt(0)" ::: "memory");   // publish complete
  int guard = 0;
  while (hsf[g * 2 + (wv ^ 1)] < ep) {
    if (++guard > 100000000) break;                    // anti-hang bailout
  }
  asm volatile("" ::: "memory");
  __builtin_amdgcn_sched_barrier(0);                   // rule 18: no hoisting
}

// ---------------- init: zero h buffers + flags, concat bias ---------------
__global__ void k_init(u32* hb, float* biasc, u32* sync,
                       const float* bi, const float* bfv,
                       const float* bo, const float* bg) {
  int i = blockIdx.x * 256 + threadIdx.x;
  if (i < 32768) {
    hb[i] = 0u;                       // both 64KB h buffers (128KB = 32768 u32)
  } else if (i < 32768 + 4096) {
    int e = i - 32768;
    int g = e >> 10, c = e & 1023;
    const float* p = (g == 0) ? bi : (g == 1) ? bfv : (g == 2) ? bo : bg;
    biasc[e] = p[c];
  } else if (i < 32768 + 4096 + 4096) {
    sync[i - 32768 - 4096] = 0u;      // 256 flags padded to 64B each
  }
}

// ---------------- transpose-cast the 8 weight matrices --------------------
// U matrices -> Ubt[e][k] row-major ([N][K] for k_gemm B operand)
// W matrices -> Wg2 K-major tiled per recurrent block:
//   off = blk*32768 + (k>>5)*1024 + rr*32 + (k&31),
//   rr = (gate<<3)|(c&7), blk = c>>3
__global__ void k_prep_w(const float* Ui, const float* Wi, const float* Uf,
                         const float* Wf, const float* Uo, const float* Wo,
                         const float* Ug, const float* Wg, u16* Ubt, u16* Wg2) {
  __shared__ float tile[64][65];
  int bx = blockIdx.x;
  int mi = bx >> 8;               // matrix 0..7 (Ui,Wi,Uf,Wf,Uo,Wo,Ug,Wg)
  int tt = bx & 255;
  int tr = tt >> 4, tc = tt & 15; // 16x16 grid of 64x64 tiles
  const float* src;
  switch (mi) {
    case 0: src = Ui; break; case 1: src = Wi; break;
    case 2: src = Uf; break; case 3: src = Wf; break;
    case 4: src = Uo; break; case 5: src = Wo; break;
    case 6: src = Ug; break; default: src = Wg; break;
  }
  int g = mi >> 1;
  int d0 = tr * 64, c0 = tc * 64;
  int ty = threadIdx.x >> 6, tx = threadIdx.x & 63;
#pragma unroll
  for (int i = 0; i < 16; ++i) {
    int r = i * 4 + ty;
    tile[r][tx] = src[(size_t)(d0 + r) * 1024 + c0 + tx];
  }
  __syncthreads();
  if (mi & 1) {
#pragma unroll
    for (int i = 0; i < 16; ++i) {
      int cc = i * 4 + ty;
      int c_full = c0 + cc;
      int k = d0 + tx;
      int blk = c_full >> 3;
      int rr = (g << 3) | (c_full & 7);
      Wg2[(size_t)blk * 32768 + ((k >> 5) << 10) + rr * 32 + (k & 31)] =
          f2bf(tile[tx][cc]);
    }
  } else {
#pragma unroll
    for (int i = 0; i < 16; ++i) {
      int cc = i * 4 + ty;
      Ubt[(size_t)((g << 10) + c0 + cc) * 1024 + d0 + tx] = f2bf(tile[tx][cc]);
    }
  }
}

// ---------------- transpose-cast X: Xt[s*32+b][d] = X[b][s][d] ------------
__global__ void k_prep_x(const float* __restrict__ X, u16* __restrict__ Xt) {
  int idx = blockIdx.x * 256 + threadIdx.x;
  int m = idx >> 8, d4 = (idx & 255) << 2;
  int s = m >> 5, b = m & 31;
  const float4* p = (const float4*)(X + (size_t)(b * SEQ + s) * DIM + d4);
  float4 v = *p;
  u16 o[4] = { f2bf(v.x), f2bf(v.y), f2bf(v.z), f2bf(v.w) };
  *(ushort4*)(Xt + (size_t)m * DIM + d4) = *(ushort4*)o;
}

// ---------------- phase 1 GEMM: xproj = Xt @ U + bias  (m97 structure) ----
__global__ __launch_bounds__(256) void k_gemm(const u16* __restrict__ Xt,
                                              const u16* __restrict__ Ubt,
                                              const float* __restrict__ biasc,
                                              u16* __restrict__ xproj) {
  __shared__ u16 As[128 * 32];
  __shared__ u16 Bs[128 * 32];
  int tid = threadIdx.x;
  int w = tid >> 6, l = tid & 63;
  int n0 = blockIdx.x * 128, m0 = blockIdx.y * 128;
  int wm = w >> 1, wn = w & 1;
  int lrow = l & 15, lq = l >> 4;
  f32x4 acc[4][4] = {};
  for (int kt = 0; kt < 32; ++kt) {
    int k0 = kt * 32;
    __syncthreads();
#pragma unroll
    for (int is = 0; is < 2; ++is) {
      int c = is * 256 + w * 64 + l;
      int row = c >> 2, kg = c & 3;
      gload_lds16(Xt + (size_t)(m0 + row) * 1024 + k0 + kg * 8, As + c * 8);
      gload_lds16(Ubt + (size_t)(n0 + row) * 1024 + k0 + kg * 8, Bs + c * 8);
    }
    __syncthreads();
    short8 af[4], bfr[4];
#pragma unroll
    for (int mt = 0; mt < 4; ++mt)
      af[mt] = *(const short8*)(As + (wm * 64 + mt * 16 + lrow) * 32 + lq * 8);
#pragma unroll
    for (int nt = 0; nt < 4; ++nt)
      bfr[nt] = *(const short8*)(Bs + (wn * 64 + nt * 16 + lrow) * 32 + lq * 8);
#pragma unroll
    for (int mt = 0; mt < 4; ++mt)
#pragma unroll
      for (int nt = 0; nt < 4; ++nt)
        acc[mt][nt] = __builtin_amdgcn_mfma_f32_16x16x32_bf16(
            af[mt], bfr[nt], acc[mt][nt], 0, 0, 0);
  }
#pragma unroll
  for (int nt = 0; nt < 4; ++nt) {
    int col = n0 + wn * 64 + nt * 16 + lrow;
    float bv = biasc[col];
#pragma unroll
    for (int mt = 0; mt < 4; ++mt) {
      int rbase = m0 + wm * 64 + mt * 16 + lq * 4;
#pragma unroll
      for (int r = 0; r < 4; ++r)
        xproj[(size_t)(rbase + r) * 4096 + col] = f2bf(acc[mt][nt][r] + bv);
    }
  }
}

// ---------------- phase 2: persistent recurrent kernel --------------------
// R7: TWO INDEPENDENT batch-group pipelines per block.
//   Group g = batches 16g..16g+15, run by waves 2g,2g+1 ("half" g).
//   Each half runs the verified R3 flag+DMA protocol for its group:
//     poll(own-group flags >= s) -> coherent DMA 32KB h(s) -> vmcnt(0)
//     -> half_sync -> MFMA (16x32 z-tile, wave wv owns 16 cols)
//     -> half_sync -> gates -> h-store -> vmcnt(2) (hst acked; out/xp fly)
//     -> half_sync -> flag = s+1
//   NO __syncthreads in the loop: halves are decoupled, so the two ~1.6us
//   latency chains overlap instead of summing. Cross-wave sync within a
//   half is LDS-flag based (half_sync).
// Protocol safety is per-group identical to R3 (hardware-verified): flag
// g/blk >= s implies that block's group-g h(s) is LLC-visible, and polling
// all 128 flags >= s before overwriting parity (s+1)&1 preserves the
// read-before-overwrite induction.
__global__ __launch_bounds__(256, 1) void k_rec(const u16* __restrict__ Wg2,
                                                const u16* __restrict__ xproj,
                                                u16* hbuf, float* out, u32* sync) {
  __shared__ u16 Ws[32 * 1024];     // 64KB, staged once (shared by both halves)
  __shared__ u16 Hs[2][16 * 1024];  // 2 x 32KB per-group h, re-staged per step
  __shared__ u16 XPs[2][2][512];    // [group][parity][16b x 32col] x_proj slice
  __shared__ float zb[2][16][33];   // per-group z tile
  __shared__ u32 hsf[4];            // half_sync flags [group*2 + wave]
  int tid = threadIdx.x;
  int w = tid >> 6, l = tid & 63;
  int g = tid >> 7;                 // group / half (0: waves 0-1, 1: waves 2-3)
  int wv = w & 1;                   // wave within half
  int blk = blockIdx.x;
  int lrow = l & 15, lq = l >> 4;
  if (tid < 4) hsf[tid] = 0u;
  // stage W slice once: linear 64KB copy (already in per-block tiled order)
#pragma unroll
  for (int it = 0; it < 16; ++it) {
    int c = it * 256 + w * 64 + l;
    gload_lds16(Wg2 + (size_t)blk * 32768 + c * 8, Ws + c * 8);
  }
  // prefetch xproj slice for s=0 (per half; both waves issue -> idempotent,
  // keeps per-wave vmcnt uniform)
  {
    int bloc = l >> 2, gs = l & 3;
    gload_lds16(xproj + (size_t)(g * 16 + bloc) * 4096 + gs * 1024 + (blk << 3),
                &XPs[g][0][l * 8]);
  }
  float c_reg = 0.f;
  int eb = (tid & 127) >> 3, ec = tid & 7;  // gate elem: batch g*16+eb, col ec
  // MFMA fragment bases: A = Hs[g] [32 tiles][16 b][32 kk] (tile stride 512)
  //                      B = Ws    [32 tiles][32 rr][32 kk] (tile stride 1024)
  const u16* ap0 = Hs[g] + lrow * 32 + lq * 8;
  const u16* bp0 = Ws + (wv * 16 + lrow) * 32 + lq * 8;
  int d = (blk << 3) + ec;
  u16* hst_base = hbuf + ((d >> 5) << 10) + (g * 16 + eb) * 32 + (d & 31);
  float* out_base = out + (size_t)(g * 16 + eb) * SEQ * DIM + d;
  const u32* syncg = sync + g * 2048;       // group's 128 flags (16-u32 pad)
  u32 epc = 0;
  __syncthreads();                   // W + XPs staged (drains vmcnt)

  for (int s = 0; s < SEQ; ++s) {
    // ---- poll own-group flags >= s (lane l covers flags l, l+64) ---------
    {
      u32 tgt = (u32)s;
      int guard = 0;
      for (;;) {
        u32 a = __hip_atomic_load(syncg + l * 16, __ATOMIC_RELAXED,
                                  __HIP_MEMORY_SCOPE_AGENT);
        u32 b = __hip_atomic_load(syncg + (64 + l) * 16, __ATOMIC_RELAXED,
                                  __HIP_MEMORY_SCOPE_AGENT);
        if (a >= tgt && b >= tgt) break;
        __builtin_amdgcn_s_sleep(1);
        if (++guard > 20000000) break;   // anti-hang bailout
      }
    }
    asm volatile("" ::: "memory");   // no hoisting DMA above the poll

    // ---- stage group h(s): wave wv stages tiles wv*16 .. wv*16+15 --------
    // global: [tile][32 b][32 kk]; group chunk = 512 u16 at tile*1024+g*512
    const u16* hsrc = hbuf + (size_t)(s & 1) * 32768 + g * 512 + l * 8;
#pragma unroll
    for (int t = 0; t < 16; ++t) {
      int tile = wv * 16 + t;
      gload_lds16_coh(hsrc + tile * 1024, Hs[g] + tile * 512 + l * 8);
    }
    asm volatile("s_waitcnt vmcnt(0)" ::: "memory");
    __builtin_amdgcn_sched_barrier(0);
    half_sync(hsf, g, wv, ++epc);    // S1: Hs[g] fully staged (both waves)

    // ---- z = h_prev @ W: wave computes 16x16 tile (cols wv*16..+15) ------
    f32x4 acc0 = { 0.f, 0.f, 0.f, 0.f };
    f32x4 acc1 = { 0.f, 0.f, 0.f, 0.f };
#pragma unroll
    for (int kk = 0; kk < 16; ++kk) {
      short8 a0 = *(const short8*)(ap0 + (2 * kk) * 512);
      short8 b0 = *(const short8*)(bp0 + (2 * kk) * 1024);
      short8 a1 = *(const short8*)(ap0 + (2 * kk + 1) * 512);
      short8 b1 = *(const short8*)(bp0 + (2 * kk + 1) * 1024);
      acc0 = __builtin_amdgcn_mfma_f32_16x16x32_bf16(a0, b0, acc0, 0, 0, 0);
      acc1 = __builtin_amdgcn_mfma_f32_16x16x32_bf16(a1, b1, acc1, 0, 0, 0);
    }
    f32x4 acc = acc0 + acc1;
    {
      int col = wv * 16 + lrow;
      int rb = lq * 4;
#pragma unroll
      for (int r = 0; r < 4; ++r) zb[g][rb + r][col] = acc[r];
    }
    half_sync(hsf, g, wv, ++epc);    // S2: zb[g] ready (both tiles)

    // ---- gates: cols 0-7=i, 8-15=f, 16-23=o, 24-31=g ---------------------
    const u16* xp = XPs[g][s & 1];
    float zi = zb[g][eb][ec]      + bf2f(xp[eb * 32 + ec]);
    float zf = zb[g][eb][8 + ec]  + bf2f(xp[eb * 32 + 8 + ec]);
    float zo = zb[g][eb][16 + ec] + bf2f(xp[eb * 32 + 16 + ec]);
    float zg = zb[g][eb][24 + ec] + bf2f(xp[eb * 32 + 24 + ec]);
    float ig = 1.f / (1.f + __expf(-zi));
    float fg = 1.f / (1.f + __expf(-zf));
    float og = 1.f / (1.f + __expf(-zo));
    float gg = tanh_fast(zg);
    c_reg = 1.f / (1.f + __expf(-(fg * c_reg + ig * gg)));  // nonstandard cell
    float h = tanh_fast(c_reg) * og;

    // write-through h store (LLC): issue order [hst][out][xp] so vmcnt(2)
    // confirms ONLY hst; out-store + xproj prefetch drain in later shadows
    __hip_atomic_store(hst_base + (size_t)((s + 1) & 1) * 32768, f2bf(h),
                       __ATOMIC_RELAXED, __HIP_MEMORY_SCOPE_AGENT);
    asm volatile("" ::: "memory");
    __builtin_nontemporal_store(h, out_base + (size_t)s * DIM);
    asm volatile("" ::: "memory");
    {
      int sp = (s + 1 < SEQ) ? s + 1 : s;
      int bloc = l >> 2, gs = l & 3;
      gload_lds16(xproj + (size_t)(sp * 32 + g * 16 + bloc) * 4096 +
                      gs * 1024 + (blk << 3),
                  &XPs[g][(s + 1) & 1][l * 8]);
    }
    asm volatile("s_waitcnt vmcnt(2)" ::: "memory");  // hst acked; out+xp fly
    __builtin_amdgcn_sched_barrier(0);
    half_sync(hsf, g, wv, ++epc);    // S3: both waves' h stores acked
    if (tid == g * 128)
      __hip_atomic_store(sync + (g * 128 + blk) * 16, (u32)(s + 1),
                         __ATOMIC_RELAXED, __HIP_MEMORY_SCOPE_AGENT);
  }
}

// ---------------------------------------------------------------------------
extern "C" void kernel_launch(void* const* d_in, const int* in_sizes, int n_in,
                              void* d_out, int out_size, void* d_ws,
                              size_t ws_size, hipStream_t stream) {
  const float* X   = (const float*)d_in[0];
  const float* Ui  = (const float*)d_in[1];
  const float* Wi  = (const float*)d_in[2];
  const float* Uf  = (const float*)d_in[3];
  const float* Wf  = (const float*)d_in[4];
  const float* Uo  = (const float*)d_in[5];
  const float* Wo  = (const float*)d_in[6];
  const float* Ug  = (const float*)d_in[7];
  const float* Wg  = (const float*)d_in[8];
  const float* bi  = (const float*)d_in[9];
  const float* bfv = (const float*)d_in[10];
  const float* bo  = (const float*)d_in[11];
  const float* bg  = (const float*)d_in[12];
  char* ws = (char*)d_ws;
  u16* Xt      = (u16*)(ws + OFF_XT);
  u16* Ubt     = (u16*)(ws + OFF_UBT);
  u16* Wg2     = (u16*)(ws + OFF_WG2);
  u16* xproj   = (u16*)(ws + OFF_XPROJ);
  u16* hbuf    = (u16*)(ws + OFF_HBUF);
  float* biasc = (float*)(ws + OFF_BIAS);
  u32* sync    = (u32*)(ws + OFF_SYNC);
  float* out   = (float*)d_out;

  k_init<<<160, 256, 0, stream>>>((u32*)hbuf, biasc, sync, bi, bfv, bo, bg);
  k_prep_w<<<2048, 256, 0, stream>>>(Ui, Wi, Uf, Wf, Uo, Wo, Ug, Wg, Ubt, Wg2);
  k_prep_x<<<16384, 256, 0, stream>>>(X, Xt);
  k_gemm<<<dim3(32, 128), 256, 0, stream>>>(Xt, Ubt, biasc, xproj);
  k_rec<<<NB, 256, 0, stream>>>(Wg2, xproj, hbuf, out, sync);
}